// Round 1
// baseline (4286.513 us; speedup 1.0000x reference)
//
#include <hip/hip_runtime.h>
#include <math.h>

// ---------------------------------------------------------------------------
// SplineCNN net: 3x spline_conv (K=36, kernel (3,4,3), open=(1,0,1)) + MLP head
// ---------------------------------------------------------------------------

#define KCONV 36

// ---- basis: B[E,8], WI[E,8] ----
__global__ void basis_kernel(const float* __restrict__ pseudo,
                             float* __restrict__ B, int* __restrict__ WI, int E) {
    int e = blockIdx.x * blockDim.x + threadIdx.x;
    if (e >= E) return;
    float f[3]; int i0[3], i1[3];
    // dim0: open, k=3
    {
        float v = pseudo[e * 3 + 0] * 2.0f;
        float fl = floorf(v); f[0] = v - fl;
        float c0 = fminf(fmaxf(fl, 0.f), 2.f);
        i0[0] = (int)c0; i1[0] = (int)fminf(c0 + 1.f, 2.f);
    }
    // dim1: closed, k=4
    {
        float v = pseudo[e * 3 + 1] * 4.0f;
        float fl = floorf(v); f[1] = v - fl;
        i0[1] = (int)fmodf(fl, 4.f); i1[1] = (int)fmodf(fl + 1.f, 4.f);
    }
    // dim2: open, k=3
    {
        float v = pseudo[e * 3 + 2] * 2.0f;
        float fl = floorf(v); f[2] = v - fl;
        float c0 = fminf(fmaxf(fl, 0.f), 2.f);
        i0[2] = (int)c0; i1[2] = (int)fminf(c0 + 1.f, 2.f);
    }
#pragma unroll
    for (int s = 0; s < 8; ++s) {
        int b0 = s & 1, b1 = (s >> 1) & 1, b2 = (s >> 2) & 1;
        float w = (b0 ? f[0] : 1.f - f[0]) * (b1 ? f[1] : 1.f - f[1]) * (b2 ? f[2] : 1.f - f[2]);
        int wi = (b0 ? i1[0] : i0[0]) * 12 + (b1 ? i1[1] : i0[1]) * 3 + (b2 ? i1[2] : i0[2]);
        B[e * 8 + s] = w;
        WI[e * 8 + s] = wi;
    }
}

__global__ void deg_kernel(const int* __restrict__ dst, float* __restrict__ deg, int E) {
    int e = blockIdx.x * blockDim.x + threadIdx.x;
    if (e < E) atomicAdd(&deg[dst[e]], 1.0f);
}

__global__ void deginv_kernel(float* __restrict__ deg, int N) {
    int i = blockIdx.x * blockDim.x + threadIdx.x;
    if (i < N) deg[i] = 1.0f / fmaxf(deg[i], 1.0f);
}

// fold deg_inv[dst] into B (valid for all 3 layers: A-row for node n is scaled by deg_inv[n])
__global__ void scaleB_kernel(float* __restrict__ B, const int* __restrict__ dst,
                              const float* __restrict__ deginv, int E) {
    int idx = blockIdx.x * blockDim.x + threadIdx.x;
    if (idx < E * 8) B[idx] *= deginv[dst[idx >> 3]];
}

// ---- scatter: A[(dst*36+wi)*F + f] += B[e,s] * x[src, f] ----
__global__ void scatter1_kernel(const float* __restrict__ x, const int* __restrict__ src,
                                const int* __restrict__ dst, const float* __restrict__ B,
                                const int* __restrict__ WI, float* __restrict__ A, int E) {
    int e = blockIdx.x * blockDim.x + threadIdx.x;
    if (e >= E) return;
    float xv = x[src[e]];
    int base = dst[e] * KCONV;
#pragma unroll
    for (int s = 0; s < 8; ++s)
        atomicAdd(&A[base + WI[e * 8 + s]], B[e * 8 + s] * xv);
}

template <int F>
__global__ void scatterF_kernel(const float* __restrict__ h, const int* __restrict__ src,
                                const int* __restrict__ dst, const float* __restrict__ B,
                                const int* __restrict__ WI, float* __restrict__ A, int E) {
    int t = blockIdx.x * blockDim.x + threadIdx.x;
    if (t >= E * F) return;
    int e = t / F, f = t % F;
    float xv = h[src[e] * F + f];
    int base = dst[e] * KCONV;
#pragma unroll
    for (int s = 0; s < 8; ++s)
        atomicAdd(&A[(base + WI[e * 8 + s]) * F + f], B[e * 8 + s] * xv);
}

// ---- generic tiled fp32 GEMM: C = A[MxK1]@W[K1xN] (+ X[MxK2]@R[K2xN]) (+bias) (relu) ----
__global__ __launch_bounds__(256) void gemm_kernel(
    const float* __restrict__ A, const float* __restrict__ W, int K1,
    const float* __restrict__ X, const float* __restrict__ R, int K2,
    const float* __restrict__ bias, float* __restrict__ C,
    int M, int N, int relu) {
    __shared__ float As[16][65];
    __shared__ float Bs[16][65];
    int t = threadIdx.x;
    int tx = t & 15, ty = t >> 4;
    int m0 = blockIdx.y * 64, n0 = blockIdx.x * 64;
    float acc[4][4] = {};
    const float* Ap = A;
    const float* Wp = W;
    int K = K1;
    for (int pass = 0; pass < 2; ++pass) {
        if (pass == 1) {
            if (K2 == 0 || X == nullptr) break;
            Ap = X; Wp = R; K = K2;
        }
        for (int k0 = 0; k0 < K; k0 += 16) {
#pragma unroll
            for (int l = 0; l < 4; ++l) {
                int idx = t + l * 256;
                int i = idx >> 4, kk = idx & 15;
                int m = m0 + i, k = k0 + kk;
                As[kk][i] = (m < M && k < K) ? Ap[(long)m * K + k] : 0.f;
            }
#pragma unroll
            for (int l = 0; l < 4; ++l) {
                int idx = t + l * 256;
                int kk = idx >> 6, j = idx & 63;
                int k = k0 + kk, n = n0 + j;
                Bs[kk][j] = (k < K && n < N) ? Wp[(long)k * N + n] : 0.f;
            }
            __syncthreads();
#pragma unroll
            for (int kk = 0; kk < 16; ++kk) {
                float a[4], b[4];
#pragma unroll
                for (int i = 0; i < 4; ++i) a[i] = As[kk][ty + 16 * i];
#pragma unroll
                for (int j = 0; j < 4; ++j) b[j] = Bs[kk][tx + 16 * j];
#pragma unroll
                for (int i = 0; i < 4; ++i)
#pragma unroll
                    for (int j = 0; j < 4; ++j) acc[i][j] += a[i] * b[j];
            }
            __syncthreads();
        }
    }
#pragma unroll
    for (int i = 0; i < 4; ++i) {
        int m = m0 + ty + 16 * i;
        if (m >= M) continue;
#pragma unroll
        for (int j = 0; j < 4; ++j) {
            int n = n0 + tx + 16 * j;
            if (n >= N) continue;
            float v = acc[i][j];
            if (bias) v += bias[n];
            if (relu) v = fmaxf(v, 0.f);
            C[(long)m * N + n] = v;
        }
    }
}

// ---- row-wise log_softmax, in place, one block per row ----
__global__ __launch_bounds__(256) void logsoftmax_kernel(float* __restrict__ out, int C) {
    int row = blockIdx.x;
    float* p = out + (long)row * C;
    __shared__ float red[256];
    float mx = -INFINITY;
    for (int c = threadIdx.x; c < C; c += 256) mx = fmaxf(mx, p[c]);
    red[threadIdx.x] = mx;
    __syncthreads();
    for (int s = 128; s > 0; s >>= 1) {
        if (threadIdx.x < s) red[threadIdx.x] = fmaxf(red[threadIdx.x], red[threadIdx.x + s]);
        __syncthreads();
    }
    mx = red[0];
    __syncthreads();
    float sum = 0.f;
    for (int c = threadIdx.x; c < C; c += 256) sum += expf(p[c] - mx);
    red[threadIdx.x] = sum;
    __syncthreads();
    for (int s = 128; s > 0; s >>= 1) {
        if (threadIdx.x < s) red[threadIdx.x] += red[threadIdx.x + s];
        __syncthreads();
    }
    float lse = logf(red[0]) + mx;
    for (int c = threadIdx.x; c < C; c += 256) p[c] = p[c] - lse;
}

extern "C" void kernel_launch(void* const* d_in, const int* in_sizes, int n_in,
                              void* d_out, int out_size, void* d_ws, size_t ws_size,
                              hipStream_t stream) {
    const float* x      = (const float*)d_in[0];   // [N,1]
    const float* pseudo = (const float*)d_in[1];   // [E,3]
    const int*   ei     = (const int*)d_in[2];     // [2,E]
    const float* W1     = (const float*)d_in[3];   // [36,1,32]
    const float* root1  = (const float*)d_in[4];   // [1,32]
    const float* b1     = (const float*)d_in[5];
    const float* W2     = (const float*)d_in[6];   // [36,32,64]
    const float* root2  = (const float*)d_in[7];   // [32,64]
    const float* b2     = (const float*)d_in[8];
    const float* W3     = (const float*)d_in[9];   // [36,64,128]
    const float* root3  = (const float*)d_in[10];  // [64,128]
    const float* b3     = (const float*)d_in[11];
    const float* lw1    = (const float*)d_in[12];  // [128,256]
    const float* lb1    = (const float*)d_in[13];
    const float* lw2    = (const float*)d_in[14];  // [256,6890]
    const float* lb2    = (const float*)d_in[15];

    const int N = in_sizes[0];      // 20000
    const int E = in_sizes[1] / 3;  // 320000
    const int Cout = 6890;
    const int* src = ei;
    const int* dst = ei + E;

    float* ws = (float*)d_ws;
    size_t off = 0;
    float* B   = ws + off; off += (size_t)E * 8;
    int*   WI  = (int*)(ws + off); off += (size_t)E * 8;
    float* deg = ws + off; off += N;            // becomes deg_inv in place
    float* h1  = ws + off; off += (size_t)N * 32;
    float* h2  = ws + off; off += (size_t)N * 64;
    float* h3  = ws + off; off += (size_t)N * 128;
    float* h4  = ws + off; off += (size_t)N * 256;
    float* A   = ws + off; off += (size_t)N * KCONV * 64;
    float* out = (float*)d_out;

    // basis + degree
    hipMemsetAsync(deg, 0, (size_t)N * sizeof(float), stream);
    basis_kernel<<<(E + 255) / 256, 256, 0, stream>>>(pseudo, B, WI, E);
    deg_kernel<<<(E + 255) / 256, 256, 0, stream>>>(dst, deg, E);
    deginv_kernel<<<(N + 255) / 256, 256, 0, stream>>>(deg, N);
    scaleB_kernel<<<(E * 8 + 255) / 256, 256, 0, stream>>>(B, dst, deg, E);

    // ---- conv layer 1: Fin=1 -> Fout=32 ----
    hipMemsetAsync(A, 0, (size_t)N * KCONV * sizeof(float), stream);
    scatter1_kernel<<<(E + 255) / 256, 256, 0, stream>>>(x, src, dst, B, WI, A, E);
    {
        dim3 g((32 + 63) / 64, (N + 63) / 64);
        gemm_kernel<<<g, 256, 0, stream>>>(A, W1, KCONV, x, root1, 1, b1, h1, N, 32, 1);
    }

    // ---- conv layer 2: Fin=32 -> Fout=64 ----
    hipMemsetAsync(A, 0, (size_t)N * KCONV * 32 * sizeof(float), stream);
    {
        long tt = (long)E * 32;
        scatterF_kernel<32><<<(tt + 255) / 256, 256, 0, stream>>>(h1, src, dst, B, WI, A, E);
        dim3 g((64 + 63) / 64, (N + 63) / 64);
        gemm_kernel<<<g, 256, 0, stream>>>(A, W2, KCONV * 32, h1, root2, 32, b2, h2, N, 64, 1);
    }

    // ---- conv layer 3: Fin=64 -> Fout=128 ----
    hipMemsetAsync(A, 0, (size_t)N * KCONV * 64 * sizeof(float), stream);
    {
        long tt = (long)E * 64;
        scatterF_kernel<64><<<(tt + 255) / 256, 256, 0, stream>>>(h2, src, dst, B, WI, A, E);
        dim3 g((128 + 63) / 64, (N + 63) / 64);
        gemm_kernel<<<g, 256, 0, stream>>>(A, W3, KCONV * 64, h2, root3, 64, b3, h3, N, 128, 1);
    }

    // ---- MLP head ----
    {
        dim3 g((256 + 63) / 64, (N + 63) / 64);
        gemm_kernel<<<g, 256, 0, stream>>>(h3, lw1, 128, nullptr, nullptr, 0, lb1, h4, N, 256, 1);
    }
    {
        dim3 g((Cout + 63) / 64, (N + 63) / 64);
        gemm_kernel<<<g, 256, 0, stream>>>(h4, lw2, 256, nullptr, nullptr, 0, lb2, out, N, Cout, 0);
    }
    logsoftmax_kernel<<<N, 256, 0, stream>>>(out, Cout);
}

// Round 2
// 2543.352 us; speedup vs baseline: 1.6854x; 1.6854x over previous
//
#include <hip/hip_runtime.h>
#include <math.h>

// ---------------------------------------------------------------------------
// SplineCNN net: 3x spline_conv (K=36, kernel (3,4,3), open=(1,0,1)) + MLP head
// GEMMs (conv2/conv3/lin1/lin2) run as bf16x3 split-precision MFMA.
// ---------------------------------------------------------------------------

#define KCONV 36

typedef __attribute__((ext_vector_type(4))) float f32x4;
typedef __attribute__((ext_vector_type(8))) short short8;

__device__ __forceinline__ unsigned bf16_rne(float x) {
    unsigned u = __builtin_bit_cast(unsigned, x);
    return (u + 0x7FFFu + ((u >> 16) & 1u)) >> 16;
}
__device__ __forceinline__ float bf16_f(unsigned h) {
    return __builtin_bit_cast(float, h << 16);
}

// ---- basis: B[E,8], WI[E,8] ----
__global__ void basis_kernel(const float* __restrict__ pseudo,
                             float* __restrict__ B, int* __restrict__ WI, int E) {
    int e = blockIdx.x * blockDim.x + threadIdx.x;
    if (e >= E) return;
    float f[3]; int i0[3], i1[3];
    {
        float v = pseudo[e * 3 + 0] * 2.0f;
        float fl = floorf(v); f[0] = v - fl;
        float c0 = fminf(fmaxf(fl, 0.f), 2.f);
        i0[0] = (int)c0; i1[0] = (int)fminf(c0 + 1.f, 2.f);
    }
    {
        float v = pseudo[e * 3 + 1] * 4.0f;
        float fl = floorf(v); f[1] = v - fl;
        i0[1] = (int)fmodf(fl, 4.f); i1[1] = (int)fmodf(fl + 1.f, 4.f);
    }
    {
        float v = pseudo[e * 3 + 2] * 2.0f;
        float fl = floorf(v); f[2] = v - fl;
        float c0 = fminf(fmaxf(fl, 0.f), 2.f);
        i0[2] = (int)c0; i1[2] = (int)fminf(c0 + 1.f, 2.f);
    }
#pragma unroll
    for (int s = 0; s < 8; ++s) {
        int b0 = s & 1, b1 = (s >> 1) & 1, b2 = (s >> 2) & 1;
        float w = (b0 ? f[0] : 1.f - f[0]) * (b1 ? f[1] : 1.f - f[1]) * (b2 ? f[2] : 1.f - f[2]);
        int wi = (b0 ? i1[0] : i0[0]) * 12 + (b1 ? i1[1] : i0[1]) * 3 + (b2 ? i1[2] : i0[2]);
        B[e * 8 + s] = w;
        WI[e * 8 + s] = wi;
    }
}

__global__ void deg_kernel(const int* __restrict__ dst, float* __restrict__ deg, int E) {
    int e = blockIdx.x * blockDim.x + threadIdx.x;
    if (e < E) atomicAdd(&deg[dst[e]], 1.0f);
}

__global__ void deginv_kernel(float* __restrict__ deg, int N) {
    int i = blockIdx.x * blockDim.x + threadIdx.x;
    if (i < N) deg[i] = 1.0f / fmaxf(deg[i], 1.0f);
}

__global__ void scaleB_kernel(float* __restrict__ B, const int* __restrict__ dst,
                              const float* __restrict__ deginv, int E) {
    int idx = blockIdx.x * blockDim.x + threadIdx.x;
    if (idx < E * 8) B[idx] *= deginv[dst[idx >> 3]];
}

// ---- scatter: A[(dst*36+wi)*F + f] += B[e,s] * x[src, f] ----
__global__ void scatter1_kernel(const float* __restrict__ x, const int* __restrict__ src,
                                const int* __restrict__ dst, const float* __restrict__ B,
                                const int* __restrict__ WI, float* __restrict__ A, int E) {
    int e = blockIdx.x * blockDim.x + threadIdx.x;
    if (e >= E) return;
    float xv = x[src[e]];
    int base = dst[e] * KCONV;
#pragma unroll
    for (int s = 0; s < 8; ++s)
        atomicAdd(&A[base + WI[e * 8 + s]], B[e * 8 + s] * xv);
}

template <int F>
__global__ void scatterF_kernel(const float* __restrict__ h, const int* __restrict__ src,
                                const int* __restrict__ dst, const float* __restrict__ B,
                                const int* __restrict__ WI, float* __restrict__ A, int E) {
    long t = (long)blockIdx.x * blockDim.x + threadIdx.x;
    if (t >= (long)E * F) return;
    int e = (int)(t / F), f = (int)(t % F);
    float xv = h[src[e] * F + f];
    int base = dst[e] * KCONV;
#pragma unroll
    for (int s = 0; s < 8; ++s)
        atomicAdd(&A[(long)(base + WI[e * 8 + s]) * F + f], B[e * 8 + s] * xv);
}

// ---- pack weights (fp32 [K1,N] + optional [K2,N]) -> bf16 hi/lo fragment layout
// layout: [Kp/32][Np/16][64 lanes][8]  (lane l holds k=(l>>4)*8+j, n=l&15)
__global__ void packB_kernel(const float* __restrict__ W, int K1,
                             const float* __restrict__ R, int K2,
                             int N, int Np,
                             unsigned short* __restrict__ Bhi,
                             unsigned short* __restrict__ Blo) {
    int ks = blockIdx.x, nf = blockIdx.y;
    int lane = threadIdx.x;
    int n = nf * 16 + (lane & 15);
    int kg = lane >> 4;
    size_t dst = (((size_t)ks * (Np >> 4) + nf) * 64 + lane) * 8;
#pragma unroll
    for (int j = 0; j < 8; ++j) {
        int k = ks * 32 + kg * 8 + j;
        float v = 0.f;
        if (n < N) v = (k < K1) ? W[(size_t)k * N + n] : R[(size_t)(k - K1) * N + n];
        unsigned h = bf16_rne(v);
        unsigned l = bf16_rne(v - bf16_f(h));
        Bhi[dst + j] = (unsigned short)h;
        Blo[dst + j] = (unsigned short)l;
    }
}

// ---- bf16x3 MFMA GEMM: C[M,N] = concat(A[M,K1],X[M,K2]) @ Bpacked (+bias)(relu)
// 128x128 tile, 4 waves of 64x64, BK=32, mfma_f32_16x16x32_bf16.
__global__ __launch_bounds__(256) void gemm_bf3_kernel(
    const float* __restrict__ A, int K1,
    const float* __restrict__ X, int K2,
    const unsigned short* __restrict__ Bhi, const unsigned short* __restrict__ Blo,
    const float* __restrict__ bias, float* __restrict__ C,
    int M, int N, int Np, int relu) {
    __shared__ unsigned short sAh[4096], sAl[4096], sBh[4096], sBl[4096];
    const int t = threadIdx.x, lane = t & 63, wave = t >> 6;
    const int wr = wave >> 1, wc = wave & 1;
    const int m0 = blockIdx.y * 128, n0 = blockIdx.x * 128;
    const int Kp = K1 + K2, nks = Kp >> 5;
    const int npf = Np >> 4;
    const int rowA = lane & 15, kg = lane >> 4;

    f32x4 acc[4][4];
#pragma unroll
    for (int i = 0; i < 4; ++i)
#pragma unroll
        for (int j = 0; j < 4; ++j) acc[i][j] = (f32x4){0.f, 0.f, 0.f, 0.f};

    for (int ks = 0; ks < nks; ++ks) {
        __syncthreads();
        // stage A: fp32 -> hi/lo bf16, fragment-linear LDS
#pragma unroll
        for (int r = 0; r < 2; ++r) {
            int fm = wave + r * 4;
            int row = m0 + fm * 16 + rowA;
            int kk = (ks << 5) + (kg << 3);
            f32x4 p0 = {0.f, 0.f, 0.f, 0.f}, p1 = {0.f, 0.f, 0.f, 0.f};
            if (row < M) {
                const float* sp = (kk < K1) ? (A + (size_t)row * K1 + kk)
                                            : (X + (size_t)row * K2 + (kk - K1));
                p0 = *(const f32x4*)sp;
                p1 = *(const f32x4*)(sp + 4);
            }
            short8 hv, lv;
#pragma unroll
            for (int j = 0; j < 8; ++j) {
                float a = (j < 4) ? p0[j] : p1[j - 4];
                unsigned h = bf16_rne(a);
                unsigned l = bf16_rne(a - bf16_f(h));
                hv[j] = (short)h;
                lv[j] = (short)l;
            }
            int doff = (fm * 64 + lane) * 8;
            *(short8*)(&sAh[doff]) = hv;
            *(short8*)(&sAl[doff]) = lv;
        }
        // stage B: packed bf16 copy
#pragma unroll
        for (int r = 0; r < 2; ++r) {
            int fn = wave + r * 4;
            size_t soff = (((size_t)ks * npf + (n0 >> 4) + fn) * 64 + lane) * 8;
            short8 hb = *(const short8*)(Bhi + soff);
            short8 lb = *(const short8*)(Blo + soff);
            int doff = (fn * 64 + lane) * 8;
            *(short8*)(&sBh[doff]) = hb;
            *(short8*)(&sBl[doff]) = lb;
        }
        __syncthreads();

        short8 ah[4], al[4], bh[4], bl[4];
#pragma unroll
        for (int i = 0; i < 4; ++i) {
            int off = ((wr * 4 + i) * 64 + lane) * 8;
            ah[i] = *(const short8*)(&sAh[off]);
            al[i] = *(const short8*)(&sAl[off]);
        }
#pragma unroll
        for (int j = 0; j < 4; ++j) {
            int off = ((wc * 4 + j) * 64 + lane) * 8;
            bh[j] = *(const short8*)(&sBh[off]);
            bl[j] = *(const short8*)(&sBl[off]);
        }
#pragma unroll
        for (int i = 0; i < 4; ++i)
#pragma unroll
            for (int j = 0; j < 4; ++j) {
                acc[i][j] = __builtin_amdgcn_mfma_f32_16x16x32_bf16(ah[i], bh[j], acc[i][j], 0, 0, 0);
                acc[i][j] = __builtin_amdgcn_mfma_f32_16x16x32_bf16(ah[i], bl[j], acc[i][j], 0, 0, 0);
                acc[i][j] = __builtin_amdgcn_mfma_f32_16x16x32_bf16(al[i], bh[j], acc[i][j], 0, 0, 0);
            }
    }

    // epilogue: C/D layout col=lane&15, row=(lane>>4)*4+reg
#pragma unroll
    for (int i = 0; i < 4; ++i) {
        int rbase = m0 + wr * 64 + i * 16 + (lane >> 4) * 4;
#pragma unroll
        for (int j = 0; j < 4; ++j) {
            int col = n0 + wc * 64 + j * 16 + (lane & 15);
            if (col >= N) continue;
            float bz = bias ? bias[col] : 0.f;
#pragma unroll
            for (int r = 0; r < 4; ++r) {
                int row = rbase + r;
                if (row < M) {
                    float v = acc[i][j][r] + bz;
                    if (relu) v = fmaxf(v, 0.f);
                    C[(size_t)row * N + col] = v;
                }
            }
        }
    }
}

// ---- fp32 fallback GEMM (conv1 only): C = A@W (+X@R) (+bias)(relu) ----
__global__ __launch_bounds__(256) void gemm_kernel(
    const float* __restrict__ A, const float* __restrict__ W, int K1,
    const float* __restrict__ X, const float* __restrict__ R, int K2,
    const float* __restrict__ bias, float* __restrict__ C,
    int M, int N, int relu) {
    __shared__ float As[16][65];
    __shared__ float Bs[16][65];
    int t = threadIdx.x;
    int tx = t & 15, ty = t >> 4;
    int m0 = blockIdx.y * 64, n0 = blockIdx.x * 64;
    float acc[4][4] = {};
    const float* Ap = A;
    const float* Wp = W;
    int K = K1;
    for (int pass = 0; pass < 2; ++pass) {
        if (pass == 1) {
            if (K2 == 0 || X == nullptr) break;
            Ap = X; Wp = R; K = K2;
        }
        for (int k0 = 0; k0 < K; k0 += 16) {
#pragma unroll
            for (int l = 0; l < 4; ++l) {
                int idx = t + l * 256;
                int i = idx >> 4, kk = idx & 15;
                int m = m0 + i, k = k0 + kk;
                As[kk][i] = (m < M && k < K) ? Ap[(long)m * K + k] : 0.f;
            }
#pragma unroll
            for (int l = 0; l < 4; ++l) {
                int idx = t + l * 256;
                int kk = idx >> 6, j = idx & 63;
                int k = k0 + kk, n = n0 + j;
                Bs[kk][j] = (k < K && n < N) ? Wp[(long)k * N + n] : 0.f;
            }
            __syncthreads();
#pragma unroll
            for (int kk = 0; kk < 16; ++kk) {
                float a[4], b[4];
#pragma unroll
                for (int i = 0; i < 4; ++i) a[i] = As[kk][ty + 16 * i];
#pragma unroll
                for (int j = 0; j < 4; ++j) b[j] = Bs[kk][tx + 16 * j];
#pragma unroll
                for (int i = 0; i < 4; ++i)
#pragma unroll
                    for (int j = 0; j < 4; ++j) acc[i][j] += a[i] * b[j];
            }
            __syncthreads();
        }
    }
#pragma unroll
    for (int i = 0; i < 4; ++i) {
        int m = m0 + ty + 16 * i;
        if (m >= M) continue;
#pragma unroll
        for (int j = 0; j < 4; ++j) {
            int n = n0 + tx + 16 * j;
            if (n >= N) continue;
            float v = acc[i][j];
            if (bias) v += bias[n];
            if (relu) v = fmaxf(v, 0.f);
            C[(long)m * N + n] = v;
        }
    }
}

// ---- row-wise log_softmax, in place, one block per row ----
__global__ __launch_bounds__(256) void logsoftmax_kernel(float* __restrict__ out, int C) {
    int row = blockIdx.x;
    float* p = out + (long)row * C;
    __shared__ float red[256];
    float mx = -INFINITY;
    for (int c = threadIdx.x; c < C; c += 256) mx = fmaxf(mx, p[c]);
    red[threadIdx.x] = mx;
    __syncthreads();
    for (int s = 128; s > 0; s >>= 1) {
        if (threadIdx.x < s) red[threadIdx.x] = fmaxf(red[threadIdx.x], red[threadIdx.x + s]);
        __syncthreads();
    }
    mx = red[0];
    __syncthreads();
    float sum = 0.f;
    for (int c = threadIdx.x; c < C; c += 256) sum += expf(p[c] - mx);
    red[threadIdx.x] = sum;
    __syncthreads();
    for (int s = 128; s > 0; s >>= 1) {
        if (threadIdx.x < s) red[threadIdx.x] += red[threadIdx.x + s];
        __syncthreads();
    }
    float lse = logf(red[0]) + mx;
    for (int c = threadIdx.x; c < C; c += 256) p[c] = p[c] - lse;
}

extern "C" void kernel_launch(void* const* d_in, const int* in_sizes, int n_in,
                              void* d_out, int out_size, void* d_ws, size_t ws_size,
                              hipStream_t stream) {
    const float* x      = (const float*)d_in[0];
    const float* pseudo = (const float*)d_in[1];
    const int*   ei     = (const int*)d_in[2];
    const float* W1     = (const float*)d_in[3];
    const float* root1  = (const float*)d_in[4];
    const float* b1     = (const float*)d_in[5];
    const float* W2     = (const float*)d_in[6];
    const float* root2  = (const float*)d_in[7];
    const float* b2     = (const float*)d_in[8];
    const float* W3     = (const float*)d_in[9];
    const float* root3  = (const float*)d_in[10];
    const float* b3     = (const float*)d_in[11];
    const float* lw1    = (const float*)d_in[12];
    const float* lb1    = (const float*)d_in[13];
    const float* lw2    = (const float*)d_in[14];
    const float* lb2    = (const float*)d_in[15];

    const int N = in_sizes[0];      // 20000
    const int E = in_sizes[1] / 3;  // 320000
    const int Cout = 6890;
    const int* src = ei;
    const int* dst = ei + E;

    float* ws = (float*)d_ws;
    size_t off = 0;
    float* B   = ws + off; off += (size_t)E * 8;
    int*   WI  = (int*)(ws + off); off += (size_t)E * 8;
    float* deg = ws + off; off += N;
    float* h1  = ws + off; off += (size_t)N * 32;
    float* h2  = ws + off; off += (size_t)N * 64;
    float* h3  = ws + off; off += (size_t)N * 128;
    float* h4  = ws + off; off += (size_t)N * 256;
    float* A   = ws + off; off += (size_t)N * KCONV * 64;
    // packed bf16 weight buffers (hi/lo), fragment layout
    unsigned short* pk = (unsigned short*)(ws + off);
    const size_t n2 = (size_t)1184 * 128, n3 = (size_t)2368 * 128;
    const size_t nl1 = (size_t)128 * 256, nl2 = (size_t)256 * 6912;
    unsigned short* B2h = pk;        pk += n2;
    unsigned short* B2l = pk;        pk += n2;
    unsigned short* B3h = pk;        pk += n3;
    unsigned short* B3l = pk;        pk += n3;
    unsigned short* L1h = pk;        pk += nl1;
    unsigned short* L1l = pk;        pk += nl1;
    unsigned short* L2h = pk;        pk += nl2;
    unsigned short* L2l = pk;        pk += nl2;
    float* out = (float*)d_out;

    // pack weights (independent of activations)
    packB_kernel<<<dim3(37, 8), 64, 0, stream>>>(W2, 1152, root2, 32, 64, 128, B2h, B2l);
    packB_kernel<<<dim3(74, 8), 64, 0, stream>>>(W3, 2304, root3, 64, 128, 128, B3h, B3l);
    packB_kernel<<<dim3(4, 16), 64, 0, stream>>>(lw1, 128, nullptr, 0, 256, 256, L1h, L1l);
    packB_kernel<<<dim3(8, 432), 64, 0, stream>>>(lw2, 256, nullptr, 0, Cout, 6912, L2h, L2l);

    // basis + degree
    hipMemsetAsync(deg, 0, (size_t)N * sizeof(float), stream);
    basis_kernel<<<(E + 255) / 256, 256, 0, stream>>>(pseudo, B, WI, E);
    deg_kernel<<<(E + 255) / 256, 256, 0, stream>>>(dst, deg, E);
    deginv_kernel<<<(N + 255) / 256, 256, 0, stream>>>(deg, N);
    scaleB_kernel<<<(E * 8 + 255) / 256, 256, 0, stream>>>(B, dst, deg, E);

    const int mt = (N + 127) / 128;  // 157 row tiles

    // ---- conv layer 1: Fin=1 -> Fout=32 (fp32 path, tiny) ----
    hipMemsetAsync(A, 0, (size_t)N * KCONV * sizeof(float), stream);
    scatter1_kernel<<<(E + 255) / 256, 256, 0, stream>>>(x, src, dst, B, WI, A, E);
    {
        dim3 g(1, (N + 63) / 64);
        gemm_kernel<<<g, 256, 0, stream>>>(A, W1, KCONV, x, root1, 1, b1, h1, N, 32, 1);
    }

    // ---- conv layer 2: Fin=32 -> Fout=64 ----
    hipMemsetAsync(A, 0, (size_t)N * KCONV * 32 * sizeof(float), stream);
    {
        long tt = (long)E * 32;
        scatterF_kernel<32><<<(tt + 255) / 256, 256, 0, stream>>>(h1, src, dst, B, WI, A, E);
        gemm_bf3_kernel<<<dim3(1, mt), 256, 0, stream>>>(A, 1152, h1, 32, B2h, B2l, b2, h2, N, 64, 128, 1);
    }

    // ---- conv layer 3: Fin=64 -> Fout=128 ----
    hipMemsetAsync(A, 0, (size_t)N * KCONV * 64 * sizeof(float), stream);
    {
        long tt = (long)E * 64;
        scatterF_kernel<64><<<(tt + 255) / 256, 256, 0, stream>>>(h2, src, dst, B, WI, A, E);
        gemm_bf3_kernel<<<dim3(1, mt), 256, 0, stream>>>(A, 2304, h2, 64, B3h, B3l, b3, h3, N, 128, 128, 1);
    }

    // ---- MLP head ----
    gemm_bf3_kernel<<<dim3(2, mt), 256, 0, stream>>>(h3, 128, nullptr, 0, L1h, L1l, lb1, h4, N, 256, 256, 1);
    gemm_bf3_kernel<<<dim3(54, mt), 256, 0, stream>>>(h4, 256, nullptr, 0, L2h, L2l, lb2, out, N, Cout, 6912, 0);
    logsoftmax_kernel<<<N, 256, 0, stream>>>(out, Cout);
}

// Round 3
// 1916.637 us; speedup vs baseline: 2.2365x; 1.3270x over previous
//
#include <hip/hip_runtime.h>
#include <math.h>

// ---------------------------------------------------------------------------
// SplineCNN net: 3x spline_conv (K=36, kernel (3,4,3), open=(1,0,1)) + MLP head
// GEMMs (conv2/conv3/lin1/lin2): bf16x3 split-precision MFMA.
// Scatter is reformulated as CSR gather with per-node LDS accumulation
// (no atomics, A written exactly once, no A memsets).
// ---------------------------------------------------------------------------

#define KCONV 36

typedef __attribute__((ext_vector_type(4))) float f32x4;
typedef __attribute__((ext_vector_type(4))) int int4v;
typedef __attribute__((ext_vector_type(8))) short short8;

__device__ __forceinline__ unsigned bf16_rne(float x) {
    unsigned u = __builtin_bit_cast(unsigned, x);
    return (u + 0x7FFFu + ((u >> 16) & 1u)) >> 16;
}
__device__ __forceinline__ float bf16_f(unsigned h) {
    return __builtin_bit_cast(float, h << 16);
}

// ---- basis: B[E,8], WI[E,8] ----
__global__ void basis_kernel(const float* __restrict__ pseudo,
                             float* __restrict__ B, int* __restrict__ WI, int E) {
    int e = blockIdx.x * blockDim.x + threadIdx.x;
    if (e >= E) return;
    float f[3]; int i0[3], i1[3];
    {
        float v = pseudo[e * 3 + 0] * 2.0f;
        float fl = floorf(v); f[0] = v - fl;
        float c0 = fminf(fmaxf(fl, 0.f), 2.f);
        i0[0] = (int)c0; i1[0] = (int)fminf(c0 + 1.f, 2.f);
    }
    {
        float v = pseudo[e * 3 + 1] * 4.0f;
        float fl = floorf(v); f[1] = v - fl;
        i0[1] = (int)fmodf(fl, 4.f); i1[1] = (int)fmodf(fl + 1.f, 4.f);
    }
    {
        float v = pseudo[e * 3 + 2] * 2.0f;
        float fl = floorf(v); f[2] = v - fl;
        float c0 = fminf(fmaxf(fl, 0.f), 2.f);
        i0[2] = (int)c0; i1[2] = (int)fminf(c0 + 1.f, 2.f);
    }
#pragma unroll
    for (int s = 0; s < 8; ++s) {
        int b0 = s & 1, b1 = (s >> 1) & 1, b2 = (s >> 2) & 1;
        float w = (b0 ? f[0] : 1.f - f[0]) * (b1 ? f[1] : 1.f - f[1]) * (b2 ? f[2] : 1.f - f[2]);
        int wi = (b0 ? i1[0] : i0[0]) * 12 + (b1 ? i1[1] : i0[1]) * 3 + (b2 ? i1[2] : i0[2]);
        B[e * 8 + s] = w;
        WI[e * 8 + s] = wi;
    }
}

// ---- CSR build ----
__global__ void hist_kernel(const int* __restrict__ dst, int* __restrict__ cnt, int E) {
    int e = blockIdx.x * blockDim.x + threadIdx.x;
    if (e < E) atomicAdd(&cnt[dst[e]], 1);
}

__global__ __launch_bounds__(1024) void scan_kernel(
    const int* __restrict__ cnt, int* __restrict__ ptr, int* __restrict__ cur,
    float* __restrict__ deginv, int N) {
    __shared__ int sdata[1024];
    __shared__ int carry;
    int tid = threadIdx.x;
    if (tid == 0) carry = 0;
    __syncthreads();
    for (int base = 0; base < N; base += 1024) {
        int i = base + tid;
        int v = (i < N) ? cnt[i] : 0;
        sdata[tid] = v;
        __syncthreads();
        for (int off = 1; off < 1024; off <<= 1) {
            int t = (tid >= off) ? sdata[tid - off] : 0;
            __syncthreads();
            sdata[tid] += t;
            __syncthreads();
        }
        int excl = carry + sdata[tid] - v;
        if (i < N) {
            ptr[i] = excl;
            cur[i] = excl;
            deginv[i] = 1.0f / fmaxf((float)v, 1.0f);
        }
        __syncthreads();
        if (tid == 0) carry += sdata[1023];
        __syncthreads();
    }
    if (tid == 0) ptr[N] = carry;
}

__global__ void fill_kernel(const int* __restrict__ dst, int* __restrict__ cur,
                            int* __restrict__ eid, int E) {
    int e = blockIdx.x * blockDim.x + threadIdx.x;
    if (e < E) {
        int p = atomicAdd(&cur[dst[e]], 1);
        eid[p] = e;
    }
}

__global__ void scaleB_kernel(float* __restrict__ B, const int* __restrict__ dst,
                              const float* __restrict__ deginv, int E) {
    int idx = blockIdx.x * blockDim.x + threadIdx.x;
    if (idx < E * 8) B[idx] *= deginv[dst[idx >> 3]];
}

// ---- gather (replaces scatter): per-node LDS accumulation, no atomics ----
__global__ __launch_bounds__(256) void gather1_kernel(
    const float* __restrict__ x, const int* __restrict__ src,
    const float* __restrict__ B, const int* __restrict__ WI,
    const int* __restrict__ ptr, const int* __restrict__ eid,
    float* __restrict__ A, int N) {
    __shared__ float accs[256 * 37];
    int t = threadIdx.x;
    int node = blockIdx.x * 256 + t;
    float* a = &accs[t * 37];
#pragma unroll
    for (int w = 0; w < KCONV; ++w) a[w] = 0.f;
    if (node >= N) return;
    int i0 = ptr[node], i1 = ptr[node + 1];
    for (int i = i0; i < i1; ++i) {
        int e = eid[i];
        float xv = x[src[e]];
        const float* Bp = B + (size_t)e * 8;
        const int* Wp = WI + (size_t)e * 8;
        f32x4 b0 = *(const f32x4*)Bp, b1 = *(const f32x4*)(Bp + 4);
        int4v w0 = *(const int4v*)Wp, w1 = *(const int4v*)(Wp + 4);
#pragma unroll
        for (int s = 0; s < 4; ++s) a[w0[s]] += b0[s] * xv;
#pragma unroll
        for (int s = 0; s < 4; ++s) a[w1[s]] += b1[s] * xv;
    }
#pragma unroll
    for (int w = 0; w < KCONV; ++w) A[(size_t)node * KCONV + w] = a[w];
}

template <int F>
__global__ __launch_bounds__(256) void gatherF_kernel(
    const float* __restrict__ h, const int* __restrict__ src,
    const float* __restrict__ B, const int* __restrict__ WI,
    const int* __restrict__ ptr, const int* __restrict__ eid,
    float* __restrict__ A, int N) {
    constexpr int NPB = 256 / F;
    __shared__ float accs[NPB * KCONV * F];
    int t = threadIdx.x;
    int f = t & (F - 1);
    int g = t / F;
    int node = blockIdx.x * NPB + g;
    float* a = &accs[(size_t)g * KCONV * F + f];
#pragma unroll
    for (int w = 0; w < KCONV; ++w) a[w * F] = 0.f;
    if (node >= N) return;
    int i0 = ptr[node], i1 = ptr[node + 1];
    for (int i = i0; i < i1; ++i) {
        int e = eid[i];
        float xv = h[(size_t)src[e] * F + f];
        const float* Bp = B + (size_t)e * 8;
        const int* Wp = WI + (size_t)e * 8;
        f32x4 b0 = *(const f32x4*)Bp, b1 = *(const f32x4*)(Bp + 4);
        int4v w0 = *(const int4v*)Wp, w1 = *(const int4v*)(Wp + 4);
#pragma unroll
        for (int s = 0; s < 4; ++s) a[w0[s] * F] += b0[s] * xv;
#pragma unroll
        for (int s = 0; s < 4; ++s) a[w1[s] * F] += b1[s] * xv;
    }
#pragma unroll
    for (int w = 0; w < KCONV; ++w)
        A[((size_t)node * KCONV + w) * F + f] = a[w * F];
}

// ---- pack weights (fp32 [K1,N] + optional [K2,N]) -> bf16 hi/lo fragment layout
__global__ void packB_kernel(const float* __restrict__ W, int K1,
                             const float* __restrict__ R, int K2,
                             int N, int Np,
                             unsigned short* __restrict__ Bhi,
                             unsigned short* __restrict__ Blo) {
    int ks = blockIdx.x, nf = blockIdx.y;
    int lane = threadIdx.x;
    int n = nf * 16 + (lane & 15);
    int kg = lane >> 4;
    size_t dst = (((size_t)ks * (Np >> 4) + nf) * 64 + lane) * 8;
#pragma unroll
    for (int j = 0; j < 8; ++j) {
        int k = ks * 32 + kg * 8 + j;
        float v = 0.f;
        if (n < N) v = (k < K1) ? W[(size_t)k * N + n] : R[(size_t)(k - K1) * N + n];
        unsigned h = bf16_rne(v);
        unsigned l = bf16_rne(v - bf16_f(h));
        Bhi[dst + j] = (unsigned short)h;
        Blo[dst + j] = (unsigned short)l;
    }
}

// ---- bf16x3 MFMA GEMM: C[M,N] = concat(A[M,K1],X[M,K2]) @ Bpacked (+bias)(relu)
__global__ __launch_bounds__(256) void gemm_bf3_kernel(
    const float* __restrict__ A, int K1,
    const float* __restrict__ X, int K2,
    const unsigned short* __restrict__ Bhi, const unsigned short* __restrict__ Blo,
    const float* __restrict__ bias, float* __restrict__ C,
    int M, int N, int Np, int relu) {
    __shared__ unsigned short sAh[4096], sAl[4096], sBh[4096], sBl[4096];
    const int t = threadIdx.x, lane = t & 63, wave = t >> 6;
    const int wr = wave >> 1, wc = wave & 1;
    const int m0 = blockIdx.y * 128, n0 = blockIdx.x * 128;
    const int Kp = K1 + K2, nks = Kp >> 5;
    const int npf = Np >> 4;
    const int rowA = lane & 15, kg = lane >> 4;

    f32x4 acc[4][4];
#pragma unroll
    for (int i = 0; i < 4; ++i)
#pragma unroll
        for (int j = 0; j < 4; ++j) acc[i][j] = (f32x4){0.f, 0.f, 0.f, 0.f};

    for (int ks = 0; ks < nks; ++ks) {
        __syncthreads();
#pragma unroll
        for (int r = 0; r < 2; ++r) {
            int fm = wave + r * 4;
            int row = m0 + fm * 16 + rowA;
            int kk = (ks << 5) + (kg << 3);
            f32x4 p0 = {0.f, 0.f, 0.f, 0.f}, p1 = {0.f, 0.f, 0.f, 0.f};
            if (row < M) {
                const float* sp = (kk < K1) ? (A + (size_t)row * K1 + kk)
                                            : (X + (size_t)row * K2 + (kk - K1));
                p0 = *(const f32x4*)sp;
                p1 = *(const f32x4*)(sp + 4);
            }
            short8 hv, lv;
#pragma unroll
            for (int j = 0; j < 8; ++j) {
                float a = (j < 4) ? p0[j] : p1[j - 4];
                unsigned h = bf16_rne(a);
                unsigned l = bf16_rne(a - bf16_f(h));
                hv[j] = (short)h;
                lv[j] = (short)l;
            }
            int doff = (fm * 64 + lane) * 8;
            *(short8*)(&sAh[doff]) = hv;
            *(short8*)(&sAl[doff]) = lv;
        }
#pragma unroll
        for (int r = 0; r < 2; ++r) {
            int fn = wave + r * 4;
            size_t soff = (((size_t)ks * npf + (n0 >> 4) + fn) * 64 + lane) * 8;
            short8 hb = *(const short8*)(Bhi + soff);
            short8 lb = *(const short8*)(Blo + soff);
            int doff = (fn * 64 + lane) * 8;
            *(short8*)(&sBh[doff]) = hb;
            *(short8*)(&sBl[doff]) = lb;
        }
        __syncthreads();

        short8 ah[4], al[4], bh[4], bl[4];
#pragma unroll
        for (int i = 0; i < 4; ++i) {
            int off = ((wr * 4 + i) * 64 + lane) * 8;
            ah[i] = *(const short8*)(&sAh[off]);
            al[i] = *(const short8*)(&sAl[off]);
        }
#pragma unroll
        for (int j = 0; j < 4; ++j) {
            int off = ((wc * 4 + j) * 64 + lane) * 8;
            bh[j] = *(const short8*)(&sBh[off]);
            bl[j] = *(const short8*)(&sBl[off]);
        }
#pragma unroll
        for (int i = 0; i < 4; ++i)
#pragma unroll
            for (int j = 0; j < 4; ++j) {
                acc[i][j] = __builtin_amdgcn_mfma_f32_16x16x32_bf16(ah[i], bh[j], acc[i][j], 0, 0, 0);
                acc[i][j] = __builtin_amdgcn_mfma_f32_16x16x32_bf16(ah[i], bl[j], acc[i][j], 0, 0, 0);
                acc[i][j] = __builtin_amdgcn_mfma_f32_16x16x32_bf16(al[i], bh[j], acc[i][j], 0, 0, 0);
            }
    }

#pragma unroll
    for (int i = 0; i < 4; ++i) {
        int rbase = m0 + wr * 64 + i * 16 + (lane >> 4) * 4;
#pragma unroll
        for (int j = 0; j < 4; ++j) {
            int col = n0 + wc * 64 + j * 16 + (lane & 15);
            if (col >= N) continue;
            float bz = bias ? bias[col] : 0.f;
#pragma unroll
            for (int r = 0; r < 4; ++r) {
                int row = rbase + r;
                if (row < M) {
                    float v = acc[i][j][r] + bz;
                    if (relu) v = fmaxf(v, 0.f);
                    C[(size_t)row * N + col] = v;
                }
            }
        }
    }
}

// ---- fp32 fallback GEMM (conv1 only) ----
__global__ __launch_bounds__(256) void gemm_kernel(
    const float* __restrict__ A, const float* __restrict__ W, int K1,
    const float* __restrict__ X, const float* __restrict__ R, int K2,
    const float* __restrict__ bias, float* __restrict__ C,
    int M, int N, int relu) {
    __shared__ float As[16][65];
    __shared__ float Bs[16][65];
    int t = threadIdx.x;
    int tx = t & 15, ty = t >> 4;
    int m0 = blockIdx.y * 64, n0 = blockIdx.x * 64;
    float acc[4][4] = {};
    const float* Ap = A;
    const float* Wp = W;
    int K = K1;
    for (int pass = 0; pass < 2; ++pass) {
        if (pass == 1) {
            if (K2 == 0 || X == nullptr) break;
            Ap = X; Wp = R; K = K2;
        }
        for (int k0 = 0; k0 < K; k0 += 16) {
#pragma unroll
            for (int l = 0; l < 4; ++l) {
                int idx = t + l * 256;
                int i = idx >> 4, kk = idx & 15;
                int m = m0 + i, k = k0 + kk;
                As[kk][i] = (m < M && k < K) ? Ap[(long)m * K + k] : 0.f;
            }
#pragma unroll
            for (int l = 0; l < 4; ++l) {
                int idx = t + l * 256;
                int kk = idx >> 6, j = idx & 63;
                int k = k0 + kk, n = n0 + j;
                Bs[kk][j] = (k < K && n < N) ? Wp[(long)k * N + n] : 0.f;
            }
            __syncthreads();
#pragma unroll
            for (int kk = 0; kk < 16; ++kk) {
                float a[4], b[4];
#pragma unroll
                for (int i = 0; i < 4; ++i) a[i] = As[kk][ty + 16 * i];
#pragma unroll
                for (int j = 0; j < 4; ++j) b[j] = Bs[kk][tx + 16 * j];
#pragma unroll
                for (int i = 0; i < 4; ++i)
#pragma unroll
                    for (int j = 0; j < 4; ++j) acc[i][j] += a[i] * b[j];
            }
            __syncthreads();
        }
    }
#pragma unroll
    for (int i = 0; i < 4; ++i) {
        int m = m0 + ty + 16 * i;
        if (m >= M) continue;
#pragma unroll
        for (int j = 0; j < 4; ++j) {
            int n = n0 + tx + 16 * j;
            if (n >= N) continue;
            float v = acc[i][j];
            if (bias) v += bias[n];
            if (relu) v = fmaxf(v, 0.f);
            C[(long)m * N + n] = v;
        }
    }
}

// ---- row-wise log_softmax, in place, one block per row ----
__global__ __launch_bounds__(256) void logsoftmax_kernel(float* __restrict__ out, int C) {
    int row = blockIdx.x;
    float* p = out + (long)row * C;
    __shared__ float red[256];
    float mx = -INFINITY;
    for (int c = threadIdx.x; c < C; c += 256) mx = fmaxf(mx, p[c]);
    red[threadIdx.x] = mx;
    __syncthreads();
    for (int s = 128; s > 0; s >>= 1) {
        if (threadIdx.x < s) red[threadIdx.x] = fmaxf(red[threadIdx.x], red[threadIdx.x + s]);
        __syncthreads();
    }
    mx = red[0];
    __syncthreads();
    float sum = 0.f;
    for (int c = threadIdx.x; c < C; c += 256) sum += expf(p[c] - mx);
    red[threadIdx.x] = sum;
    __syncthreads();
    for (int s = 128; s > 0; s >>= 1) {
        if (threadIdx.x < s) red[threadIdx.x] += red[threadIdx.x + s];
        __syncthreads();
    }
    float lse = logf(red[0]) + mx;
    for (int c = threadIdx.x; c < C; c += 256) p[c] = p[c] - lse;
}

extern "C" void kernel_launch(void* const* d_in, const int* in_sizes, int n_in,
                              void* d_out, int out_size, void* d_ws, size_t ws_size,
                              hipStream_t stream) {
    const float* x      = (const float*)d_in[0];
    const float* pseudo = (const float*)d_in[1];
    const int*   ei     = (const int*)d_in[2];
    const float* W1     = (const float*)d_in[3];
    const float* root1  = (const float*)d_in[4];
    const float* b1     = (const float*)d_in[5];
    const float* W2     = (const float*)d_in[6];
    const float* root2  = (const float*)d_in[7];
    const float* b2     = (const float*)d_in[8];
    const float* W3     = (const float*)d_in[9];
    const float* root3  = (const float*)d_in[10];
    const float* b3     = (const float*)d_in[11];
    const float* lw1    = (const float*)d_in[12];
    const float* lb1    = (const float*)d_in[13];
    const float* lw2    = (const float*)d_in[14];
    const float* lb2    = (const float*)d_in[15];

    const int N = in_sizes[0];      // 20000
    const int E = in_sizes[1] / 3;  // 320000
    const int Cout = 6890;
    const int* src = ei;
    const int* dst = ei + E;

    float* ws = (float*)d_ws;
    size_t off = 0;
    float* B      = ws + off; off += (size_t)E * 8;
    int*   WI     = (int*)(ws + off); off += (size_t)E * 8;
    float* deginv = ws + off; off += N;
    int*   cnt    = (int*)(ws + off); off += N;
    int*   ptr    = (int*)(ws + off); off += N + 1;
    int*   cur    = (int*)(ws + off); off += N;
    int*   eid    = (int*)(ws + off); off += E;
    float* h1  = ws + off; off += (size_t)N * 32;
    float* h2  = ws + off; off += (size_t)N * 64;
    float* h3  = ws + off; off += (size_t)N * 128;
    float* h4  = ws + off; off += (size_t)N * 256;
    float* A   = ws + off; off += (size_t)N * KCONV * 64;
    unsigned short* pk = (unsigned short*)(ws + off);
    const size_t n2 = (size_t)1184 * 128, n3 = (size_t)2368 * 128;
    const size_t nl1 = (size_t)128 * 256, nl2 = (size_t)256 * 6912;
    unsigned short* B2h = pk;        pk += n2;
    unsigned short* B2l = pk;        pk += n2;
    unsigned short* B3h = pk;        pk += n3;
    unsigned short* B3l = pk;        pk += n3;
    unsigned short* L1h = pk;        pk += nl1;
    unsigned short* L1l = pk;        pk += nl1;
    unsigned short* L2h = pk;        pk += nl2;
    unsigned short* L2l = pk;        pk += nl2;
    float* out = (float*)d_out;

    // pack weights (independent of activations)
    packB_kernel<<<dim3(37, 8), 64, 0, stream>>>(W2, 1152, root2, 32, 64, 128, B2h, B2l);
    packB_kernel<<<dim3(74, 8), 64, 0, stream>>>(W3, 2304, root3, 64, 128, 128, B3h, B3l);
    packB_kernel<<<dim3(4, 16), 64, 0, stream>>>(lw1, 128, nullptr, 0, 256, 256, L1h, L1l);
    packB_kernel<<<dim3(8, 432), 64, 0, stream>>>(lw2, 256, nullptr, 0, Cout, 6912, L2h, L2l);

    // basis + CSR build
    basis_kernel<<<(E + 255) / 256, 256, 0, stream>>>(pseudo, B, WI, E);
    hipMemsetAsync(cnt, 0, (size_t)N * sizeof(int), stream);
    hist_kernel<<<(E + 255) / 256, 256, 0, stream>>>(dst, cnt, E);
    scan_kernel<<<1, 1024, 0, stream>>>(cnt, ptr, cur, deginv, N);
    scaleB_kernel<<<(E * 8 + 255) / 256, 256, 0, stream>>>(B, dst, deginv, E);
    fill_kernel<<<(E + 255) / 256, 256, 0, stream>>>(dst, cur, eid, E);

    const int mt = (N + 127) / 128;  // row tiles

    // ---- conv layer 1: Fin=1 -> Fout=32 ----
    gather1_kernel<<<(N + 255) / 256, 256, 0, stream>>>(x, src, B, WI, ptr, eid, A, N);
    {
        dim3 g(1, (N + 63) / 64);
        gemm_kernel<<<g, 256, 0, stream>>>(A, W1, KCONV, x, root1, 1, b1, h1, N, 32, 1);
    }

    // ---- conv layer 2: Fin=32 -> Fout=64 ----
    gatherF_kernel<32><<<(N + 7) / 8, 256, 0, stream>>>(h1, src, B, WI, ptr, eid, A, N);
    gemm_bf3_kernel<<<dim3(1, mt), 256, 0, stream>>>(A, 1152, h1, 32, B2h, B2l, b2, h2, N, 64, 128, 1);

    // ---- conv layer 3: Fin=64 -> Fout=128 ----
    gatherF_kernel<64><<<(N + 3) / 4, 256, 0, stream>>>(h2, src, B, WI, ptr, eid, A, N);
    gemm_bf3_kernel<<<dim3(1, mt), 256, 0, stream>>>(A, 2304, h2, 64, B3h, B3l, b3, h3, N, 128, 128, 1);

    // ---- MLP head ----
    gemm_bf3_kernel<<<dim3(2, mt), 256, 0, stream>>>(h3, 128, nullptr, 0, L1h, L1l, lb1, h4, N, 256, 256, 1);
    gemm_bf3_kernel<<<dim3(54, mt), 256, 0, stream>>>(h4, 256, nullptr, 0, L2h, L2l, lb2, out, N, Cout, 6912, 0);
    logsoftmax_kernel<<<N, 256, 0, stream>>>(out, Cout);
}

// Round 7
// 1709.006 us; speedup vs baseline: 2.5082x; 1.1215x over previous
//
#include <hip/hip_runtime.h>
#include <math.h>

// ---------------------------------------------------------------------------
// SplineCNN net: 3x spline_conv (K=36, kernel (3,4,3), open=(1,0,1)) + MLP head
// conv2/conv3 GEMMs: bf16x3 split-precision MFMA (fp32 A, split in-kernel).
// lin1: bf16x3 MFMA, epilogue writes h4 as packed hi/lo bf16 fragments.
// lin2: packed-A/packed-B MFMA GEMM + global_load_lds + XCD swizzle +
//       fused partial-LSE epilogue; lse-combine + subtract replace logsoftmax.
// Scatter is CSR gather with per-node LDS accumulation (no atomics).
// ---------------------------------------------------------------------------

#define KCONV 36

typedef __attribute__((ext_vector_type(4))) float f32x4;
typedef __attribute__((ext_vector_type(4))) int int4v;
typedef __attribute__((ext_vector_type(8))) short short8;

typedef const unsigned __attribute__((address_space(1)))* gasp;
typedef unsigned __attribute__((address_space(3)))* lasp;

// global->LDS direct copy, 16B per lane; LDS dest is wave-uniform base,
// HW writes lane i at base + i*16.
__device__ __forceinline__ void gld16(const void* g, unsigned short* l) {
    __builtin_amdgcn_global_load_lds((gasp)g, (lasp)l, 16, 0, 0);
}

__device__ __forceinline__ unsigned bf16_rne(float x) {
    unsigned u = __builtin_bit_cast(unsigned, x);
    return (u + 0x7FFFu + ((u >> 16) & 1u)) >> 16;
}
__device__ __forceinline__ float bf16_f(unsigned h) {
    return __builtin_bit_cast(float, h << 16);
}

// ---- basis: B[E,8], WI[E,8] ----
__global__ void basis_kernel(const float* __restrict__ pseudo,
                             float* __restrict__ B, int* __restrict__ WI, int E) {
    int e = blockIdx.x * blockDim.x + threadIdx.x;
    if (e >= E) return;
    float f[3]; int i0[3], i1[3];
    {
        float v = pseudo[e * 3 + 0] * 2.0f;
        float fl = floorf(v); f[0] = v - fl;
        float c0 = fminf(fmaxf(fl, 0.f), 2.f);
        i0[0] = (int)c0; i1[0] = (int)fminf(c0 + 1.f, 2.f);
    }
    {
        float v = pseudo[e * 3 + 1] * 4.0f;
        float fl = floorf(v); f[1] = v - fl;
        i0[1] = (int)fmodf(fl, 4.f); i1[1] = (int)fmodf(fl + 1.f, 4.f);
    }
    {
        float v = pseudo[e * 3 + 2] * 2.0f;
        float fl = floorf(v); f[2] = v - fl;
        float c0 = fminf(fmaxf(fl, 0.f), 2.f);
        i0[2] = (int)c0; i1[2] = (int)fminf(c0 + 1.f, 2.f);
    }
#pragma unroll
    for (int s = 0; s < 8; ++s) {
        int b0 = s & 1, b1 = (s >> 1) & 1, b2 = (s >> 2) & 1;
        float w = (b0 ? f[0] : 1.f - f[0]) * (b1 ? f[1] : 1.f - f[1]) * (b2 ? f[2] : 1.f - f[2]);
        int wi = (b0 ? i1[0] : i0[0]) * 12 + (b1 ? i1[1] : i0[1]) * 3 + (b2 ? i1[2] : i0[2]);
        B[e * 8 + s] = w;
        WI[e * 8 + s] = wi;
    }
}

// ---- CSR build ----
__global__ void hist_kernel(const int* __restrict__ dst, int* __restrict__ cnt, int E) {
    int e = blockIdx.x * blockDim.x + threadIdx.x;
    if (e < E) atomicAdd(&cnt[dst[e]], 1);
}

__global__ __launch_bounds__(1024) void scan_kernel(
    const int* __restrict__ cnt, int* __restrict__ ptr, int* __restrict__ cur,
    float* __restrict__ deginv, int N) {
    __shared__ int wsum[16];
    __shared__ int carry_s;
    int tid = threadIdx.x, lane = tid & 63, wid = tid >> 6;
    if (tid == 0) carry_s = 0;
    __syncthreads();
    for (int base = 0; base < N; base += 1024) {
        int i = base + tid;
        int v = (i < N) ? cnt[i] : 0;
        int x = v;
        for (int off = 1; off < 64; off <<= 1) {
            int t = __shfl_up(x, off, 64);
            if (lane >= off) x += t;
        }
        if (lane == 63) wsum[wid] = x;
        int carry = carry_s;
        __syncthreads();
        if (wid == 0) {
            int w = (lane < 16) ? wsum[lane] : 0;
            for (int off = 1; off < 16; off <<= 1) {
                int t = __shfl_up(w, off, 64);
                if (lane >= off) w += t;
            }
            if (lane < 16) wsum[lane] = w;
        }
        __syncthreads();
        int wexcl = (wid == 0) ? 0 : wsum[wid - 1];
        int excl = carry + wexcl + x - v;
        if (i < N) {
            ptr[i] = excl;
            cur[i] = excl;
            deginv[i] = 1.0f / fmaxf((float)v, 1.0f);
        }
        __syncthreads();
        if (tid == 0) carry_s = carry + wsum[15];
        __syncthreads();
    }
    if (threadIdx.x == 0) ptr[N] = carry_s;
}

__global__ void fill_kernel(const int* __restrict__ dst, int* __restrict__ cur,
                            int* __restrict__ eid, int E) {
    int e = blockIdx.x * blockDim.x + threadIdx.x;
    if (e < E) {
        int p = atomicAdd(&cur[dst[e]], 1);
        eid[p] = e;
    }
}

__global__ void scaleB_kernel(float* __restrict__ B, const int* __restrict__ dst,
                              const float* __restrict__ deginv, int E) {
    int idx = blockIdx.x * blockDim.x + threadIdx.x;
    if (idx < E * 8) B[idx] *= deginv[dst[idx >> 3]];
}

// ---- gather: per-node LDS accumulation, no atomics ----
__global__ __launch_bounds__(256) void gather1_kernel(
    const float* __restrict__ x, const int* __restrict__ src,
    const float* __restrict__ B, const int* __restrict__ WI,
    const int* __restrict__ ptr, const int* __restrict__ eid,
    float* __restrict__ A, int N) {
    __shared__ float accs[256 * 37];
    int t = threadIdx.x;
    int node = blockIdx.x * 256 + t;
    float* a = &accs[t * 37];
#pragma unroll
    for (int w = 0; w < KCONV; ++w) a[w] = 0.f;
    if (node >= N) return;
    int i0 = ptr[node], i1 = ptr[node + 1];
    for (int i = i0; i < i1; ++i) {
        int e = eid[i];
        float xv = x[src[e]];
        const float* Bp = B + (size_t)e * 8;
        const int* Wp = WI + (size_t)e * 8;
        f32x4 b0 = *(const f32x4*)Bp, b1 = *(const f32x4*)(Bp + 4);
        int4v w0 = *(const int4v*)Wp, w1 = *(const int4v*)(Wp + 4);
#pragma unroll
        for (int s = 0; s < 4; ++s) a[w0[s]] += b0[s] * xv;
#pragma unroll
        for (int s = 0; s < 4; ++s) a[w1[s]] += b1[s] * xv;
    }
#pragma unroll
    for (int w = 0; w < KCONV; ++w) A[(size_t)node * KCONV + w] = a[w];
}

template <int F>
__global__ __launch_bounds__(256) void gatherF_kernel(
    const float* __restrict__ h, const int* __restrict__ src,
    const float* __restrict__ B, const int* __restrict__ WI,
    const int* __restrict__ ptr, const int* __restrict__ eid,
    float* __restrict__ A, int N) {
    constexpr int NPB = 256 / F;
    __shared__ float accs[NPB * KCONV * F];
    int t = threadIdx.x;
    int f = t & (F - 1);
    int g = t / F;
    int node = blockIdx.x * NPB + g;
    float* a = &accs[(size_t)g * KCONV * F + f];
#pragma unroll
    for (int w = 0; w < KCONV; ++w) a[w * F] = 0.f;
    if (node >= N) return;
    int i0 = ptr[node], i1 = ptr[node + 1];
    for (int i = i0; i < i1; ++i) {
        int e = eid[i];
        float xv = h[(size_t)src[e] * F + f];
        const float* Bp = B + (size_t)e * 8;
        const int* Wp = WI + (size_t)e * 8;
        f32x4 b0 = *(const f32x4*)Bp, b1 = *(const f32x4*)(Bp + 4);
        int4v w0 = *(const int4v*)Wp, w1 = *(const int4v*)(Wp + 4);
#pragma unroll
        for (int s = 0; s < 4; ++s) a[w0[s] * F] += b0[s] * xv;
#pragma unroll
        for (int s = 0; s < 4; ++s) a[w1[s] * F] += b1[s] * xv;
    }
#pragma unroll
    for (int w = 0; w < KCONV; ++w)
        A[((size_t)node * KCONV + w) * F + f] = a[w * F];
}

// ---- pack weights (fp32 [K1,N] + optional [K2,N]) -> bf16 hi/lo fragment layout
// layout: [Kp/32][Np/16][64 lanes][8]  (lane l holds k=(l>>4)*8+j, n=l&15)
__global__ void packB_kernel(const float* __restrict__ W, int K1,
                             const float* __restrict__ R, int K2,
                             int N, int Np,
                             unsigned short* __restrict__ Bhi,
                             unsigned short* __restrict__ Blo) {
    int ks = blockIdx.x, nf = blockIdx.y;
    int lane = threadIdx.x;
    int n = nf * 16 + (lane & 15);
    int kg = lane >> 4;
    size_t dst = (((size_t)ks * (Np >> 4) + nf) * 64 + lane) * 8;
#pragma unroll
    for (int j = 0; j < 8; ++j) {
        int k = ks * 32 + kg * 8 + j;
        float v = 0.f;
        if (n < N) v = (k < K1) ? W[(size_t)k * N + n] : R[(size_t)(k - K1) * N + n];
        unsigned h = bf16_rne(v);
        unsigned l = bf16_rne(v - bf16_f(h));
        Bhi[dst + j] = (unsigned short)h;
        Blo[dst + j] = (unsigned short)l;
    }
}

// ---- bf16x3 MFMA GEMM (fp32 A, split in-kernel): conv2/conv3 ----
__global__ __launch_bounds__(256) void gemm_bf3_kernel(
    const float* __restrict__ A, int K1,
    const float* __restrict__ X, int K2,
    const unsigned short* __restrict__ Bhi, const unsigned short* __restrict__ Blo,
    const float* __restrict__ bias, float* __restrict__ C,
    int M, int N, int Np, int relu) {
    __shared__ unsigned short sAh[4096], sAl[4096], sBh[4096], sBl[4096];
    const int t = threadIdx.x, lane = t & 63, wave = t >> 6;
    const int wr = wave >> 1, wc = wave & 1;
    const int m0 = blockIdx.y * 128, n0 = blockIdx.x * 128;
    const int Kp = K1 + K2, nks = Kp >> 5;
    const int npf = Np >> 4;
    const int rowA = lane & 15, kg = lane >> 4;

    f32x4 acc[4][4];
#pragma unroll
    for (int i = 0; i < 4; ++i)
#pragma unroll
        for (int j = 0; j < 4; ++j) acc[i][j] = (f32x4){0.f, 0.f, 0.f, 0.f};

    for (int ks = 0; ks < nks; ++ks) {
        __syncthreads();
#pragma unroll
        for (int r = 0; r < 2; ++r) {
            int fm = wave + r * 4;
            int row = m0 + fm * 16 + rowA;
            int kk = (ks << 5) + (kg << 3);
            f32x4 p0 = {0.f, 0.f, 0.f, 0.f}, p1 = {0.f, 0.f, 0.f, 0.f};
            if (row < M) {
                const float* sp = (kk < K1) ? (A + (size_t)row * K1 + kk)
                                            : (X + (size_t)row * K2 + (kk - K1));
                p0 = *(const f32x4*)sp;
                p1 = *(const f32x4*)(sp + 4);
            }
            short8 hv, lv;
#pragma unroll
            for (int j = 0; j < 8; ++j) {
                float a = (j < 4) ? p0[j] : p1[j - 4];
                unsigned h = bf16_rne(a);
                unsigned l = bf16_rne(a - bf16_f(h));
                hv[j] = (short)h;
                lv[j] = (short)l;
            }
            int doff = (fm * 64 + lane) * 8;
            *(short8*)(&sAh[doff]) = hv;
            *(short8*)(&sAl[doff]) = lv;
        }
#pragma unroll
        for (int r = 0; r < 2; ++r) {
            int fn = wave + r * 4;
            size_t soff = (((size_t)ks * npf + (n0 >> 4) + fn) * 64 + lane) * 8;
            short8 hb = *(const short8*)(Bhi + soff);
            short8 lb = *(const short8*)(Blo + soff);
            int doff = (fn * 64 + lane) * 8;
            *(short8*)(&sBh[doff]) = hb;
            *(short8*)(&sBl[doff]) = lb;
        }
        __syncthreads();

        short8 ah[4], al[4], bh[4], bl[4];
#pragma unroll
        for (int i = 0; i < 4; ++i) {
            int off = ((wr * 4 + i) * 64 + lane) * 8;
            ah[i] = *(const short8*)(&sAh[off]);
            al[i] = *(const short8*)(&sAl[off]);
        }
#pragma unroll
        for (int j = 0; j < 4; ++j) {
            int off = ((wc * 4 + j) * 64 + lane) * 8;
            bh[j] = *(const short8*)(&sBh[off]);
            bl[j] = *(const short8*)(&sBl[off]);
        }
#pragma unroll
        for (int i = 0; i < 4; ++i)
#pragma unroll
            for (int j = 0; j < 4; ++j) {
                acc[i][j] = __builtin_amdgcn_mfma_f32_16x16x32_bf16(ah[i], bh[j], acc[i][j], 0, 0, 0);
                acc[i][j] = __builtin_amdgcn_mfma_f32_16x16x32_bf16(ah[i], bl[j], acc[i][j], 0, 0, 0);
                acc[i][j] = __builtin_amdgcn_mfma_f32_16x16x32_bf16(al[i], bh[j], acc[i][j], 0, 0, 0);
            }
    }

#pragma unroll
    for (int i = 0; i < 4; ++i) {
        int rbase = m0 + wr * 64 + i * 16 + (lane >> 4) * 4;
#pragma unroll
        for (int j = 0; j < 4; ++j) {
            int col = n0 + wc * 64 + j * 16 + (lane & 15);
            if (col >= N) continue;
            float bz = bias ? bias[col] : 0.f;
#pragma unroll
            for (int r = 0; r < 4; ++r) {
                int row = rbase + r;
                if (row < M) {
                    float v = acc[i][j][r] + bz;
                    if (relu) v = fmaxf(v, 0.f);
                    C[(size_t)row * N + col] = v;
                }
            }
        }
    }
}

// ---- lin1: same GEMM body, epilogue writes relu(out) as packed hi/lo bf16
// fragments [row/16][k/32][64][8] (A-operand layout for lin2). N == Np == 256.
__global__ __launch_bounds__(256) void gemm_bf3p_kernel(
    const float* __restrict__ A, int K1,
    const unsigned short* __restrict__ Bhi, const unsigned short* __restrict__ Blo,
    const float* __restrict__ bias,
    unsigned short* __restrict__ Ph, unsigned short* __restrict__ Pl,
    int nkso, int M, int N, int Np) {
    __shared__ unsigned short sAh[4096], sAl[4096], sBh[4096], sBl[4096];
    const int t = threadIdx.x, lane = t & 63, wave = t >> 6;
    const int wr = wave >> 1, wc = wave & 1;
    const int m0 = blockIdx.y * 128, n0 = blockIdx.x * 128;
    const int nks = K1 >> 5;
    const int npf = Np >> 4;
    const int rowA = lane & 15, kg = lane >> 4;
    const int l15 = lane & 15;

    f32x4 acc[4][4];
#pragma unroll
    for (int i = 0; i < 4; ++i)
#pragma unroll
        for (int j = 0; j < 4; ++j) acc[i][j] = (f32x4){0.f, 0.f, 0.f, 0.f};

    for (int ks = 0; ks < nks; ++ks) {
        __syncthreads();
#pragma unroll
        for (int r = 0; r < 2; ++r) {
            int fm = wave + r * 4;
            int row = m0 + fm * 16 + rowA;
            int kk = (ks << 5) + (kg << 3);
            f32x4 p0 = {0.f, 0.f, 0.f, 0.f}, p1 = {0.f, 0.f, 0.f, 0.f};
            if (row < M) {
                const float* sp = A + (size_t)row * K1 + kk;
                p0 = *(const f32x4*)sp;
                p1 = *(const f32x4*)(sp + 4);
            }
            short8 hv, lv;
#pragma unroll
            for (int j = 0; j < 8; ++j) {
                float a = (j < 4) ? p0[j] : p1[j - 4];
                unsigned h = bf16_rne(a);
                unsigned l = bf16_rne(a - bf16_f(h));
                hv[j] = (short)h;
                lv[j] = (short)l;
            }
            int doff = (fm * 64 + lane) * 8;
            *(short8*)(&sAh[doff]) = hv;
            *(short8*)(&sAl[doff]) = lv;
        }
#pragma unroll
        for (int r = 0; r < 2; ++r) {
            int fn = wave + r * 4;
            size_t soff = (((size_t)ks * npf + (n0 >> 4) + fn) * 64 + lane) * 8;
            short8 hb = *(const short8*)(Bhi + soff);
            short8 lb = *(const short8*)(Blo + soff);
            int doff = (fn * 64 + lane) * 8;
            *(short8*)(&sBh[doff]) = hb;
            *(short8*)(&sBl[doff]) = lb;
        }
        __syncthreads();

        short8 ah[4], al[4], bh[4], bl[4];
#pragma unroll
        for (int i = 0; i < 4; ++i) {
            int off = ((wr * 4 + i) * 64 + lane) * 8;
            ah[i] = *(const short8*)(&sAh[off]);
            al[i] = *(const short8*)(&sAl[off]);
        }
#pragma unroll
        for (int j = 0; j < 4; ++j) {
            int off = ((wc * 4 + j) * 64 + lane) * 8;
            bh[j] = *(const short8*)(&sBh[off]);
            bl[j] = *(const short8*)(&sBl[off]);
        }
#pragma unroll
        for (int i = 0; i < 4; ++i)
#pragma unroll
            for (int j = 0; j < 4; ++j) {
                acc[i][j] = __builtin_amdgcn_mfma_f32_16x16x32_bf16(ah[i], bh[j], acc[i][j], 0, 0, 0);
                acc[i][j] = __builtin_amdgcn_mfma_f32_16x16x32_bf16(ah[i], bl[j], acc[i][j], 0, 0, 0);
                acc[i][j] = __builtin_amdgcn_mfma_f32_16x16x32_bf16(al[i], bh[j], acc[i][j], 0, 0, 0);
            }
    }

    // packed epilogue: element (row, k=col) -> frag (row>>4, col>>5),
    // lane' = (row&15) + ((col>>3)&3)*16, j' = col&7
#pragma unroll
    for (int i = 0; i < 4; ++i) {
        int rf = (m0 >> 4) + wr * 4 + i;
#pragma unroll
        for (int j = 0; j < 4; ++j) {
            int col = n0 + wc * 64 + j * 16 + l15;
            float bz = bias[col];
            int ks = col >> 5;
            int lanep = (kg * 4) + ((col >> 3) & 3) * 16;
            int jj = col & 7;
#pragma unroll
            for (int r = 0; r < 4; ++r) {
                int row = m0 + wr * 64 + i * 16 + kg * 4 + r;
                if (row >= M) continue;
                float v = fmaxf(acc[i][j][r] + bz, 0.f);
                unsigned h = bf16_rne(v);
                unsigned lo = bf16_rne(v - bf16_f(h));
                size_t di = (((size_t)rf * nkso + ks) * 64 + lanep + r) * 8 + jj;
                Ph[di] = (unsigned short)h;
                Pl[di] = (unsigned short)lo;
            }
        }
    }
}

// ---- lin2: packed-A, packed-B MFMA GEMM + global_load_lds + XCD swizzle +
// fused partial-LSE epilogue (per row, per 64-col half-tile) ----
__global__ __launch_bounds__(256) void gemm_lse_kernel(
    const unsigned short* __restrict__ Ah, const unsigned short* __restrict__ Al,
    const unsigned short* __restrict__ Bh, const unsigned short* __restrict__ Bl,
    const float* __restrict__ bias, float* __restrict__ C,
    float* __restrict__ pm, float* __restrict__ pl,
    int M, int N, int nks, int npf, int nct, int nrt, int Mpad) {
    __shared__ unsigned short sAh[4096], sAl[4096], sBh[4096], sBl[4096];
    const int t = threadIdx.x, lane = t & 63, wave = t >> 6;
    const int wr = wave >> 1, wc = wave & 1;
    const int kg = lane >> 4, l15 = lane & 15;

    // bijective chunked XCD swizzle (rt-major within chunk -> A panel L2 reuse)
    int bid = blockIdx.x;
    int nwg = nct * nrt;
    int xcd = bid & 7, loc = bid >> 3;
    int q = nwg >> 3, r8 = nwg & 7;
    int wg = (xcd < r8 ? xcd * (q + 1) : r8 * (q + 1) + (xcd - r8) * q) + loc;
    int rt = wg / nct, ct = wg - rt * nct;
    const int m0 = rt * 128, n0 = ct * 128;

    f32x4 acc[4][4];
#pragma unroll
    for (int i = 0; i < 4; ++i)
#pragma unroll
        for (int j = 0; j < 4; ++j) acc[i][j] = (f32x4){0.f, 0.f, 0.f, 0.f};

    for (int ks = 0; ks < nks; ++ks) {
        __syncthreads();
#pragma unroll
        for (int r2 = 0; r2 < 2; ++r2) {
            int fm = wave + r2 * 4;
            size_t afo = (((size_t)(rt * 8 + fm) * nks + ks) * 1024) + (size_t)lane * 16;
            size_t bfo = (((size_t)ks * npf + ct * 8 + fm) * 1024) + (size_t)lane * 16;
            gld16((const char*)Ah + afo, &sAh[fm * 512]);
            gld16((const char*)Al + afo, &sAl[fm * 512]);
            gld16((const char*)Bh + bfo, &sBh[fm * 512]);
            gld16((const char*)Bl + bfo, &sBl[fm * 512]);
        }
        __syncthreads();

        short8 ah[4], al[4], bh[4], bl[4];
#pragma unroll
        for (int i = 0; i < 4; ++i) {
            int off = ((wr * 4 + i) * 64 + lane) * 8;
            ah[i] = *(const short8*)(&sAh[off]);
            al[i] = *(const short8*)(&sAl[off]);
        }
#pragma unroll
        for (int j = 0; j < 4; ++j) {
            int off = ((wc * 4 + j) * 64 + lane) * 8;
            bh[j] = *(const short8*)(&sBh[off]);
            bl[j] = *(const short8*)(&sBl[off]);
        }
#pragma unroll
        for (int i = 0; i < 4; ++i)
#pragma unroll
            for (int j = 0; j < 4; ++j) {
                acc[i][j] = __builtin_amdgcn_mfma_f32_16x16x32_bf16(ah[i], bh[j], acc[i][j], 0, 0, 0);
                acc[i][j] = __builtin_amdgcn_mfma_f32_16x16x32_bf16(ah[i], bl[j], acc[i][j], 0, 0, 0);
                acc[i][j] = __builtin_amdgcn_mfma_f32_16x16x32_bf16(al[i], bh[j], acc[i][j], 0, 0, 0);
            }
    }

    // epilogue: store logits + per-row partial (max, sumexp) over this wave's
    // 64 cols; 16-lane shuffle reduce (lanes l15=0..15 share a row)
#pragma unroll
    for (int i = 0; i < 4; ++i) {
#pragma unroll
        for (int r = 0; r < 4; ++r) {
            int row = m0 + wr * 64 + i * 16 + kg * 4 + r;
            float v[4];
            float rmax = -INFINITY;
#pragma unroll
            for (int j = 0; j < 4; ++j) {
                int col = n0 + wc * 64 + j * 16 + l15;
                if (col < N) {
                    float tv = acc[i][j][r] + bias[col];
                    v[j] = tv;
                    if (row < M) C[(size_t)row * N + col] = tv;
                    rmax = fmaxf(rmax, tv);
                } else {
                    v[j] = -INFINITY;
                }
            }
#pragma unroll
            for (int o = 1; o < 16; o <<= 1) rmax = fmaxf(rmax, __shfl_xor(rmax, o, 64));
            float s = 0.f;
#pragma unroll
            for (int j = 0; j < 4; ++j)
                if (v[j] != -INFINITY) s += __expf(v[j] - rmax);
#pragma unroll
            for (int o = 1; o < 16; o <<= 1) s += __shfl_xor(s, o, 64);
            if (l15 == 0 && row < M) {
                int pidx = ct * 2 + wc;
                pm[(size_t)pidx * Mpad + row] = rmax;
                pl[(size_t)pidx * Mpad + row] = s;
            }
        }
    }
}

// ---- combine partial (m,l) -> lse per row ----
__global__ void lse_kernel(const float* __restrict__ pm, const float* __restrict__ pl,
                           float* __restrict__ lse, int M, int Mpad, int np) {
    int rix = blockIdx.x * 256 + threadIdx.x;
    if (rix >= M) return;
    float m = -INFINITY, l = 0.f;
    for (int p = 0; p < np; ++p) {
        float mp = pm[(size_t)p * Mpad + rix];
        float lp = pl[(size_t)p * Mpad + rix];
        float mn = fmaxf(m, mp);
        l = l * expf(m - mn) + lp * expf(mp - mn);
        m = mn;
    }
    lse[rix] = m + logf(l);
}

// ---- out[row, :] -= lse[row], float2 vectorized ----
__global__ __launch_bounds__(256) void sub_kernel(float* __restrict__ out,
                                                  const float* __restrict__ lse, int C) {
    int row = blockIdx.x;
    float s = lse[row];
    float2* p = (float2*)(out + (size_t)row * C);
    int n2 = C >> 1;
    for (int c = threadIdx.x; c < n2; c += 256) {
        float2 v = p[c];
        v.x -= s; v.y -= s;
        p[c] = v;
    }
}

// ---- fp32 fallback GEMM (conv1 only) ----
__global__ __launch_bounds__(256) void gemm_kernel(
    const float* __restrict__ A, const float* __restrict__ W, int K1,
    const float* __restrict__ X, const float* __restrict__ R, int K2,
    const float* __restrict__ bias, float* __restrict__ C,
    int M, int N, int relu) {
    __shared__ float As[16][65];
    __shared__ float Bs[16][65];
    int t = threadIdx.x;
    int tx = t & 15, ty = t >> 4;
    int m0 = blockIdx.y * 64, n0 = blockIdx.x * 64;
    float acc[4][4] = {};
    const float* Ap = A;
    const float* Wp = W;
    int K = K1;
    for (int pass = 0; pass < 2; ++pass) {
        if (pass == 1) {
            if (K2 == 0 || X == nullptr) break;
            Ap = X; Wp = R; K = K2;
        }
        for (int k0 = 0; k0 < K; k0 += 16) {
#pragma unroll
            for (int l = 0; l < 4; ++l) {
                int idx = t + l * 256;
                int i = idx >> 4, kk = idx & 15;
                int m = m0 + i, k = k0 + kk;
                As[kk][i] = (m < M && k < K) ? Ap[(long)m * K + k] : 0.f;
            }
#pragma unroll
            for (int l = 0; l < 4; ++l) {
                int idx = t + l * 256;
                int kk = idx >> 6, j = idx & 63;
                int k = k0 + kk, n = n0 + j;
                Bs[kk][j] = (k < K && n < N) ? Wp[(long)k * N + n] : 0.f;
            }
            __syncthreads();
#pragma unroll
            for (int kk = 0; kk < 16; ++kk) {
                float a[4], b[4];
#pragma unroll
                for (int i = 0; i < 4; ++i) a[i] = As[kk][ty + 16 * i];
#pragma unroll
                for (int j = 0; j < 4; ++j) b[j] = Bs[kk][tx + 16 * j];
#pragma unroll
                for (int i = 0; i < 4; ++i)
#pragma unroll
                    for (int j = 0; j < 4; ++j) acc[i][j] += a[i] * b[j];
            }
            __syncthreads();
        }
    }
#pragma unroll
    for (int i = 0; i < 4; ++i) {
        int m = m0 + ty + 16 * i;
        if (m >= M) continue;
#pragma unroll
        for (int j = 0; j < 4; ++j) {
            int n = n0 + tx + 16 * j;
            if (n >= N) continue;
            float v = acc[i][j];
            if (bias) v += bias[n];
            if (relu) v = fmaxf(v, 0.f);
            C[(long)m * N + n] = v;
        }
    }
}

extern "C" void kernel_launch(void* const* d_in, const int* in_sizes, int n_in,
                              void* d_out, int out_size, void* d_ws, size_t ws_size,
                              hipStream_t stream) {
    const float* x      = (const float*)d_in[0];
    const float* pseudo = (const float*)d_in[1];
    const int*   ei     = (const int*)d_in[2];
    const float* W1     = (const float*)d_in[3];
    const float* root1  = (const float*)d_in[4];
    const float* b1     = (const float*)d_in[5];
    const float* W2     = (const float*)d_in[6];
    const float* root2  = (const float*)d_in[7];
    const float* b2     = (const float*)d_in[8];
    const float* W3     = (const float*)d_in[9];
    const float* root3  = (const float*)d_in[10];
    const float* b3     = (const float*)d_in[11];
    const float* lw1    = (const float*)d_in[12];
    const float* lb1    = (const float*)d_in[13];
    const float* lw2    = (const float*)d_in[14];
    const float* lb2    = (const float*)d_in[15];

    const int N = in_sizes[0];      // 20000
    const int E = in_sizes[1] / 3;  // 320000
    const int Cout = 6890;
    const int* src = ei;
    const int* dst = ei + E;

    const int mt = (N + 127) / 128;     // 157 row tiles
    const int Mpad = mt * 128;          // 20096
    const int nct = 54;                 // 6912 / 128 col tiles for lin2
    const int nrf = Mpad / 16;          // 1256 row frags

    float* ws = (float*)d_ws;
    size_t off = 0;
    float* B      = ws + off; off += (size_t)E * 8;
    int*   WI     = (int*)(ws + off); off += (size_t)E * 8;
    float* deginv = ws + off; off += N;
    int*   cnt    = (int*)(ws + off); off += N;
    int*   ptr    = (int*)(ws + off); off += N + 1;
    int*   cur    = (int*)(ws + off); off += N;
    int*   eid    = (int*)(ws + off); off += E;
    float* h1  = ws + off; off += (size_t)N * 32;
    float* h2  = ws + off; off += (size_t)N * 64;
    float* h3  = ws + off; off += (size_t)N * 128;
    float* A   = ws + off; off += (size_t)N * KCONV * 64;
    unsigned short* pk = (unsigned short*)(ws + off);
    const size_t n2 = (size_t)37 * 8 * 512, n3 = (size_t)74 * 8 * 512;
    const size_t nl1 = (size_t)4 * 16 * 512, nl2 = (size_t)8 * 432 * 512;
    const size_t na4 = (size_t)nrf * 8 * 512;
    unsigned short* B2h = pk;        pk += n2;
    unsigned short* B2l = pk;        pk += n2;
    unsigned short* B3h = pk;        pk += n3;
    unsigned short* B3l = pk;        pk += n3;
    unsigned short* L1h = pk;        pk += nl1;
    unsigned short* L1l = pk;        pk += nl1;
    unsigned short* L2h = pk;        pk += nl2;
    unsigned short* L2l = pk;        pk += nl2;
    unsigned short* A4h = pk;        pk += na4;
    unsigned short* A4l = pk;        pk += na4;
    float* pmb = (float*)pk;
    float* plb = pmb + (size_t)nct * 2 * Mpad;
    float* lseb = plb + (size_t)nct * 2 * Mpad;
    float* out = (float*)d_out;

    // pack weights
    packB_kernel<<<dim3(37, 8), 64, 0, stream>>>(W2, 1152, root2, 32, 64, 128, B2h, B2l);
    packB_kernel<<<dim3(74, 8), 64, 0, stream>>>(W3, 2304, root3, 64, 128, 128, B3h, B3l);
    packB_kernel<<<dim3(4, 16), 64, 0, stream>>>(lw1, 128, nullptr, 0, 256, 256, L1h, L1l);
    packB_kernel<<<dim3(8, 432), 64, 0, stream>>>(lw2, 256, nullptr, 0, Cout, 6912, L2h, L2l);

    // basis + CSR build
    basis_kernel<<<(E + 255) / 256, 256, 0, stream>>>(pseudo, B, WI, E);
    hipMemsetAsync(cnt, 0, (size_t)N * sizeof(int), stream);
    hist_kernel<<<(E + 255) / 256, 256, 0, stream>>>(dst, cnt, E);
    scan_kernel<<<1, 1024, 0, stream>>>(cnt, ptr, cur, deginv, N);
    scaleB_kernel<<<(E * 8 + 255) / 256, 256, 0, stream>>>(B, dst, deginv, E);
    fill_kernel<<<(E + 255) / 256, 256, 0, stream>>>(dst, cur, eid, E);

    // ---- conv layer 1: Fin=1 -> Fout=32 ----
    gather1_kernel<<<(N + 255) / 256, 256, 0, stream>>>(x, src, B, WI, ptr, eid, A, N);
    {
        dim3 g(1, (N + 63) / 64);
        gemm_kernel<<<g, 256, 0, stream>>>(A, W1, KCONV, x, root1, 1, b1, h1, N, 32, 1);
    }

    // ---- conv layer 2: Fin=32 -> Fout=64 ----
    gatherF_kernel<32><<<(N + 7) / 8, 256, 0, stream>>>(h1, src, B, WI, ptr, eid, A, N);
    gemm_bf3_kernel<<<dim3(1, mt), 256, 0, stream>>>(A, 1152, h1, 32, B2h, B2l, b2, h2, N, 64, 128, 1);

    // ---- conv layer 3: Fin=64 -> Fout=128 ----
    gatherF_kernel<64><<<(N + 3) / 4, 256, 0, stream>>>(h2, src, B, WI, ptr, eid, A, N);
    gemm_bf3_kernel<<<dim3(1, mt), 256, 0, stream>>>(A, 2304, h2, 64, B3h, B3l, b3, h3, N, 128, 128, 1);

    // ---- lin1: h3[20000,128] @ lw1[128,256] -> packed h4 fragments ----
    gemm_bf3p_kernel<<<dim3(2, mt), 256, 0, stream>>>(h3, 128, L1h, L1l, lb1, A4h, A4l, 8, N, 256, 256);

    // ---- lin2 + fused partial-LSE, then combine + subtract ----
    gemm_lse_kernel<<<nct * mt, 256, 0, stream>>>(A4h, A4l, L2h, L2l, lb2, out,
                                                  pmb, plb, N, Cout, 8, 432, nct, mt, Mpad);
    lse_kernel<<<(N + 255) / 256, 256, 0, stream>>>(pmb, plb, lseb, N, Mpad, nct * 2);
    sub_kernel<<<N, 256, 0, stream>>>(out, lseb, Cout);
}